// Round 12
// baseline (141.674 us; speedup 1.0000x reference)
//
#include <hip/hip_runtime.h>
#include <stdint.h>

#define NB 4
#define SS 192
#define NI 256

typedef __attribute__((ext_vector_type(8))) short bf16x8;
typedef __attribute__((ext_vector_type(16))) float f32x16;

__device__ __forceinline__ uint16_t f2bf(float f) {
  union { float f; uint32_t u; } v; v.f = f;
  return (uint16_t)((v.u + 0x7FFFu + ((v.u >> 16) & 1u)) >> 16);
}

__device__ __forceinline__ uint4 pack8(const float4 a, const float4 b) {
  uint4 r;
  r.x = (uint32_t)f2bf(a.x) | ((uint32_t)f2bf(a.y) << 16);
  r.y = (uint32_t)f2bf(a.z) | ((uint32_t)f2bf(a.w) << 16);
  r.z = (uint32_t)f2bf(b.x) | ((uint32_t)f2bf(b.y) << 16);
  r.w = (uint32_t)f2bf(b.z) | ((uint32_t)f2bf(b.w) << 16);
  return r;
}

// load 8 consecutive f32 and convert to a bf16x8 MFMA fragment
__device__ __forceinline__ bf16x8 ldcvt8(const float* p) {
  const float4 x = *(const float4*)p;
  const float4 y = *(const float4*)(p + 4);
  union { uint4 u; bf16x8 v; } r;
  r.u = pack8(x, y);
  return r.v;
}

__device__ __forceinline__ uint32_t bfmul2(uint32_t x, uint32_t y) {
  union { float f; uint32_t u; } xa, xb, ya, yb, r0, r1;
  xa.u = x << 16;        ya.u = y << 16;
  xb.u = x & 0xFFFF0000u; yb.u = y & 0xFFFF0000u;
  r0.f = xa.f * ya.f;
  r1.f = xb.f * yb.f;
  uint32_t lo = (r0.u + 0x7FFFu + ((r0.u >> 16) & 1u)) >> 16;
  uint32_t hi = (r1.u + 0x7FFFu + ((r1.u >> 16) & 1u)) >> 16;
  return lo | (hi << 16);
}

// ---------------- K_A: fused scores (0..11) + HH/HS converts (12..59) + W partials (60..1083) ----------------
// 512 threads. Score block (which,b): phase1 Q = A1 x B1^T (MFMA, frags from
// global f32 + in-reg cvt) -> LDS bf16 swizzled; phase2 S = A2 x Q^T -> global f32.
__global__ __launch_bounds__(512) void kA(
    const float* __restrict__ W,
    const float* __restrict__ h_head, const float* __restrict__ h_dep, const float* __restrict__ h_sib,
    const float* __restrict__ U, const float* __restrict__ V, const float* __restrict__ Z,
    float* __restrict__ partial,
    uint16_t* __restrict__ HH, uint16_t* __restrict__ HS,
    float* __restrict__ s_hd, float* __restrict__ s_hs, float* __restrict__ s_ds) {
  __shared__ __align__(16) uint16_t Qs[SS * NI];   // 96 KB
  __shared__ float red[8];
  const int bi = blockIdx.x, tid = threadIdx.x;

  if (bi >= 60) {
    // ---- W chunk: sum 16384 consecutive floats ----
    const int c = bi - 60;                       // 0..1023
    const float4* pw = (const float4*)(W + (size_t)c * 16384);
    float4 a = {0.f, 0.f, 0.f, 0.f};
    #pragma unroll
    for (int it = 0; it < 8; ++it) {
      const float4 v = pw[it * 512 + tid];
      a.x += v.x; a.y += v.y; a.z += v.z; a.w += v.w;
    }
    float s = (a.x + a.y) + (a.z + a.w);
    for (int off = 32; off > 0; off >>= 1) s += __shfl_down(s, off, 64);
    if ((tid & 63) == 0) red[tid >> 6] = s;
    __syncthreads();
    if (tid == 0) {
      float t = 0.f;
      #pragma unroll
      for (int q = 0; q < 8; ++q) t += red[q];
      partial[c] = t;
    }
    return;
  }
  if (bi >= 12) {
    // ---- converts: canonical swizzled bf16 storage for k3 (HH, HS) ----
    const int rl = tid >> 5, c8 = tid & 31;
    const int g = (bi - 12) * 16 + rl;           // 0..767
    const int dst = g * 32 + (c8 ^ (g & 15));
    const int srci = g * 64 + c8 * 2;
    { const float4 x = ((const float4*)h_head)[srci], y = ((const float4*)h_head)[srci + 1];
      ((uint4*)HH)[dst] = pack8(x, y); }
    { const float4 x = ((const float4*)h_sib)[srci], y = ((const float4*)h_sib)[srci + 1];
      ((uint4*)HS)[dst] = pack8(x, y); }
    return;
  }

  // ---- fused score unit ----
  const int which = bi >> 2, b = bi & 3;
  const float* A1 = (which == 0) ? h_dep : h_sib;
  const float* B1 = (which == 0) ? U : (which == 1) ? V : Z;
  const float* A2 = (which == 2) ? h_dep : h_head;
  float* Os = (which == 0) ? s_hd : (which == 1) ? s_hs : s_ds;
  const int lane = tid & 63, w = tid >> 6;
  const int l31 = lane & 31, l5 = lane >> 5;

  // phase 1: Q[m=192 (A1 rows)][n=256 (B1 rows)] ; wave = one 32-wide n-strip
  {
    const int n0 = w * 32;
    f32x16 qa[6] = {};
    #pragma unroll
    for (int ks = 0; ks < 16; ++ks) {
      const int kcol = ks * 16 + l5 * 8;
      const bf16x8 bf = ldcvt8(B1 + (size_t)(n0 + l31) * NI + kcol);
      #pragma unroll
      for (int mt = 0; mt < 6; ++mt) {
        const bf16x8 af = ldcvt8(A1 + (size_t)(b * SS + mt * 32 + l31) * NI + kcol);
        qa[mt] = __builtin_amdgcn_mfma_f32_32x32x16_bf16(af, bf, qa[mt], 0, 0, 0);
      }
    }
    const int n = n0 + l31;
    #pragma unroll
    for (int mt = 0; mt < 6; ++mt)
      #pragma unroll
      for (int r = 0; r < 16; ++r) {
        const int m = mt * 32 + (r & 3) + 8 * (r >> 2) + 4 * l5;
        *(uint16_t*)((char*)Qs + m * 512 + ((((n >> 3) ^ (m & 15))) << 4) + (n & 7) * 2)
            = f2bf(qa[mt][r]);
      }
  }
  __syncthreads();

  // phase 2: S[m=192 (A2 rows)][n=192 (Q rows)] ; waves 0..5, one n-strip each
  if (w < 6) {
    const int n0 = w * 32;
    f32x16 sa[6] = {};
    #pragma unroll
    for (int ks = 0; ks < 16; ++ks) {
      const int sl = ks * 2 + l5;
      const int brow = n0 + l31;
      const bf16x8 bf = *reinterpret_cast<const bf16x8*>(
          (const char*)Qs + brow * 512 + ((sl ^ (brow & 15)) << 4));
      const int kcol = ks * 16 + l5 * 8;
      #pragma unroll
      for (int mt = 0; mt < 6; ++mt) {
        const bf16x8 af = ldcvt8(A2 + (size_t)(b * SS + mt * 32 + l31) * NI + kcol);
        sa[mt] = __builtin_amdgcn_mfma_f32_32x32x16_bf16(af, bf, sa[mt], 0, 0, 0);
      }
    }
    #pragma unroll
    for (int mt = 0; mt < 6; ++mt)
      #pragma unroll
      for (int r = 0; r < 16; ++r) {
        const int m = mt * 32 + (r & 3) + 8 * (r >> 2) + 4 * l5;
        Os[(size_t)(b * SS + m) * SS + (n0 + l31)] = sa[mt][r];
      }
  }
}

// ---------------- K3: main GEMM (R11-validated body; partial count 1024) ----------------
__global__ __launch_bounds__(384, 3) void k3_big(
    const uint16_t* __restrict__ HH, const uint16_t* __restrict__ HS,
    const float* __restrict__ h_dep, const float* __restrict__ partial,
    const float* __restrict__ s_hd, const float* __restrict__ s_hs,
    const float* __restrict__ s_ds,
    const float* __restrict__ bias, float* __restrict__ out) {
  __shared__ __align__(16) uint16_t Btile[SS * 128];   // 48 KB
  __shared__ __align__(16) uint16_t Atile[96 * 128];   // 24 KB
  __shared__ uint16_t cvec[NI];
  const int d = blockIdx.x, hb = blockIdx.y, b = blockIdx.z;
  const int tid = threadIdx.x;
  const int lane = tid & 63, w = tid >> 6;
  const int whb = (w >> 1) * 32;
  const int wsb = (w & 1) * 96;
  const int l31 = lane & 31, l5 = lane >> 5;

  if (tid < NI) {
    const float wr = partial[4 * tid] + partial[4 * tid + 1]
                   + partial[4 * tid + 2] + partial[4 * tid + 3];
    cvec[tid] = f2bf(wr * h_dep[(b * SS + d) * NI + tid]);
  }
  __syncthreads();

  f32x16 acc0 = {}, acc1 = {}, acc2 = {};

  #pragma unroll
  for (int half = 0; half < 2; ++half) {
    const int kbase = half * 128;
    #pragma unroll
    for (int i = 0; i < 8; ++i) {
      const int slot = (w * 8 + i) * 64 + lane;
      const int row = slot >> 4;
      const uint16_t* src = HS + ((size_t)(b * SS + row) << 8) + kbase + (slot & 15) * 8;
      __builtin_amdgcn_global_load_lds(
          (const __attribute__((address_space(1))) void*)src,
          (__attribute__((address_space(3))) void*)(Btile + (size_t)slot * 8),
          16, 0, 0);
    }
    #pragma unroll
    for (int i = 0; i < 4; ++i) {
      const int c = i * 384 + tid;
      const int row = c >> 4;
      const int kc = c & 15;
      const int lcl = kc ^ (row & 15);
      const uint4 cv4 = *(const uint4*)(cvec + kbase + lcl * 8);
      const uint4 hh4 = *(const uint4*)(HH + ((size_t)(b * SS + hb * 96 + row) << 8) + kbase + kc * 8);
      uint4 a4;
      a4.x = bfmul2(hh4.x, cv4.x);
      a4.y = bfmul2(hh4.y, cv4.y);
      a4.z = bfmul2(hh4.z, cv4.z);
      a4.w = bfmul2(hh4.w, cv4.w);
      *(uint4*)((char*)Atile + row * 256 + (kc << 4)) = a4;
    }
    __syncthreads();
    const int arow = whb + l31;
    const int abyte = arow * 256;
    const int amask = (arow & 15);
    #pragma unroll
    for (int ks = 0; ks < 8; ++ks) {
      const int sl = ks * 2 + l5;
      bf16x8 af = *reinterpret_cast<const bf16x8*>((const char*)Atile + abyte + ((sl ^ amask) << 4));
      {
        const int brow = wsb + l31;
        bf16x8 bf = *reinterpret_cast<const bf16x8*>((const char*)Btile + brow * 256 + ((sl ^ (brow & 15)) << 4));
        acc0 = __builtin_amdgcn_mfma_f32_32x32x16_bf16(af, bf, acc0, 0, 0, 0);
      }
      {
        const int brow = wsb + 32 + l31;
        bf16x8 bf = *reinterpret_cast<const bf16x8*>((const char*)Btile + brow * 256 + ((sl ^ (brow & 15)) << 4));
        acc1 = __builtin_amdgcn_mfma_f32_32x32x16_bf16(af, bf, acc1, 0, 0, 0);
      }
      {
        const int brow = wsb + 64 + l31;
        bf16x8 bf = *reinterpret_cast<const bf16x8*>((const char*)Btile + brow * 256 + ((sl ^ (brow & 15)) << 4));
        acc2 = __builtin_amdgcn_mfma_f32_32x32x16_bf16(af, bf, acc2, 0, 0, 0);
      }
    }
    __syncthreads();
  }

  const float bias0 = bias[0];
  float chd[16];
  #pragma unroll
  for (int r = 0; r < 16; ++r) {
    const int h = hb * 96 + whb + (r & 3) + 8 * (r >> 2) + 4 * l5;
    chd[r] = s_hd[(b * SS + h) * SS + d] + bias0;
  }
  #pragma unroll
  for (int t = 0; t < 3; ++t) {
    const int s = wsb + t * 32 + l31;
    const float dsv = s_ds[(b * SS + d) * SS + s];
    const f32x16 a = (t == 0) ? acc0 : (t == 1) ? acc1 : acc2;
    #pragma unroll
    for (int r = 0; r < 16; ++r) {
      const int h = hb * 96 + whb + (r & 3) + 8 * (r >> 2) + 4 * l5;
      const float v = a[r] + chd[r] + s_hs[(b * SS + h) * SS + s] + dsv;
      out[((size_t)(b * SS + h) * SS + d) * SS + s] = v;
    }
  }
}

extern "C" void kernel_launch(void* const* d_in, const int* in_sizes, int n_in,
                              void* d_out, int out_size, void* d_ws, size_t ws_size,
                              hipStream_t stream) {
  const float* h_head = (const float*)d_in[0];
  const float* h_dep  = (const float*)d_in[1];
  const float* h_sib  = (const float*)d_in[2];
  const float* W_tri  = (const float*)d_in[3];
  const float* U_hd   = (const float*)d_in[4];
  const float* V_hs   = (const float*)d_in[5];
  const float* Z_ds   = (const float*)d_in[6];
  const float* bias   = (const float*)d_in[7];
  float* out = (float*)d_out;

  float* ws = (float*)d_ws;
  float* partial = ws;          ws += 1024;
  float* s_hd    = ws;          ws += NB * SS * SS;
  float* s_hs    = ws;          ws += NB * SS * SS;
  float* s_ds    = ws;          ws += NB * SS * SS;
  uint16_t* HH   = (uint16_t*)ws;
  uint16_t* HS   = HH + NB * SS * NI;

  kA<<<1084, 512, 0, stream>>>(W_tri, h_head, h_dep, h_sib, U_hd, V_hs, Z_ds,
                               partial, HH, HS, s_hd, s_hs, s_ds);
  k3_big<<<dim3(SS, 2, NB), 384, 0, stream>>>(HH, HS, h_dep, partial,
                                              s_hd, s_hs, s_ds, bias, out);
}

// Round 14
// 78.068 us; speedup vs baseline: 1.8148x; 1.8148x over previous
//
#include <hip/hip_runtime.h>
#include <stdint.h>

#define NB 4
#define SS 192
#define NI 256

typedef __attribute__((ext_vector_type(8))) short bf16x8;
typedef __attribute__((ext_vector_type(16))) float f32x16;

__device__ __forceinline__ uint16_t f2bf(float f) {
  union { float f; uint32_t u; } v; v.f = f;
  return (uint16_t)((v.u + 0x7FFFu + ((v.u >> 16) & 1u)) >> 16);
}

__device__ __forceinline__ uint4 pack8(const float4 a, const float4 b) {
  uint4 r;
  r.x = (uint32_t)f2bf(a.x) | ((uint32_t)f2bf(a.y) << 16);
  r.y = (uint32_t)f2bf(a.z) | ((uint32_t)f2bf(a.w) << 16);
  r.z = (uint32_t)f2bf(b.x) | ((uint32_t)f2bf(b.y) << 16);
  r.w = (uint32_t)f2bf(b.z) | ((uint32_t)f2bf(b.w) << 16);
  return r;
}

__device__ __forceinline__ uint32_t bfmul2(uint32_t x, uint32_t y) {
  union { float f; uint32_t u; } xa, xb, ya, yb, r0, r1;
  xa.u = x << 16;        ya.u = y << 16;
  xb.u = x & 0xFFFF0000u; yb.u = y & 0xFFFF0000u;
  r0.f = xa.f * ya.f;
  r1.f = xb.f * yb.f;
  uint32_t lo = (r0.u + 0x7FFFu + ((r0.u >> 16) & 1u)) >> 16;
  uint32_t hi = (r1.u + 0x7FFFu + ((r1.u >> 16) & 1u)) >> 16;
  return lo | (hi << 16);
}

// Canonical bf16 storage: row-major, 8-elem chunks permuted c8 -> c8 ^ (row&15).
// partial[] contract: 2048 chunks of 8192 floats; w_red[i] = sum(partial[8i..8i+7]).

// ---------------- K0: W_tri partials (0..2047) + bf16 converts (2048..2175) ----------------
__global__ __launch_bounds__(256) void k0(
    const float* __restrict__ W,
    const float* __restrict__ h_head, const float* __restrict__ h_dep, const float* __restrict__ h_sib,
    const float* __restrict__ U, const float* __restrict__ V, const float* __restrict__ Z,
    float* __restrict__ partial,
    uint16_t* __restrict__ HH, uint16_t* __restrict__ HD, uint16_t* __restrict__ HS,
    uint16_t* __restrict__ U16, uint16_t* __restrict__ V16, uint16_t* __restrict__ Z16) {
  __shared__ float red[4];
  const int bi = blockIdx.x, tid = threadIdx.x;
  if (bi < 2048) {
    const float4* pw = (const float4*)(W + (size_t)bi * 8192);
    float4 a = {0.f, 0.f, 0.f, 0.f};
    #pragma unroll
    for (int it = 0; it < 8; ++it) {
      const float4 v = pw[it * 256 + tid];
      a.x += v.x; a.y += v.y; a.z += v.z; a.w += v.w;
    }
    float s = (a.x + a.y) + (a.z + a.w);
    for (int off = 32; off > 0; off >>= 1) s += __shfl_down(s, off, 64);
    if ((tid & 63) == 0) red[tid >> 6] = s;
    __syncthreads();
    if (tid == 0) partial[bi] = red[0] + red[1] + red[2] + red[3];
    return;
  }
  const int rl = tid >> 5, c8 = tid & 31;
  if (bi < 2144) {
    const int g = (bi - 2048) * 8 + rl;            // 0..767
    const int dst = g * 32 + (c8 ^ (g & 15));
    const int srci = g * 64 + c8 * 2;
    { const float4 x = ((const float4*)h_head)[srci], y = ((const float4*)h_head)[srci + 1];
      ((uint4*)HH)[dst] = pack8(x, y); }
    { const float4 x = ((const float4*)h_dep)[srci], y = ((const float4*)h_dep)[srci + 1];
      ((uint4*)HD)[dst] = pack8(x, y); }
    { const float4 x = ((const float4*)h_sib)[srci], y = ((const float4*)h_sib)[srci + 1];
      ((uint4*)HS)[dst] = pack8(x, y); }
  } else {
    const int g = (bi - 2144) * 8 + rl;            // 0..255
    const int dst = g * 32 + (c8 ^ (g & 15));
    const int srci = g * 64 + c8 * 2;
    { const float4 x = ((const float4*)U)[srci], y = ((const float4*)U)[srci + 1];
      ((uint4*)U16)[dst] = pack8(x, y); }
    { const float4 x = ((const float4*)V)[srci], y = ((const float4*)V)[srci + 1];
      ((uint4*)V16)[dst] = pack8(x, y); }
    { const float4 x = ((const float4*)Z)[srci], y = ((const float4*)Z)[srci + 1];
      ((uint4*)Z16)[dst] = pack8(x, y); }
  }
}

// ---------------- K1 stage-1: dU/T2/TZ = A(192xK) x B(U/V/Z rows)^T, MFMA ----------------
__global__ __launch_bounds__(256, 2) void k_s1(
    const uint16_t* __restrict__ HD, const uint16_t* __restrict__ HS,
    const uint16_t* __restrict__ U16, const uint16_t* __restrict__ V16, const uint16_t* __restrict__ Z16,
    uint16_t* __restrict__ dU16, uint16_t* __restrict__ T216, uint16_t* __restrict__ TZ16) {
  __shared__ __align__(16) uint16_t Ah[192 * 128];   // 48 KB
  __shared__ __align__(16) uint16_t Bh[128 * 128];   // 32 KB
  const int which = blockIdx.x, nt = blockIdx.y, b = blockIdx.z;
  const uint16_t* As = (which == 0) ? HD : HS;
  const uint16_t* Bs = (which == 0) ? U16 : (which == 1) ? V16 : Z16;
  uint16_t* Os = (which == 0) ? dU16 : (which == 1) ? T216 : TZ16;
  const int tid = threadIdx.x, lane = tid & 63, w = tid >> 6;
  const int l31 = lane & 31, l5 = lane >> 5;
  const int N0 = nt * 128;
  f32x16 acc[6] = {};

  #pragma unroll
  for (int kh = 0; kh < 2; ++kh) {
    const int kbase = kh * 128;
    if (kh) __syncthreads();
    #pragma unroll
    for (int i = 0; i < 12; ++i) {
      const int slot = i * 256 + tid;
      const int row = slot >> 4, ck = slot & 15;
      const uint16_t* src = As + (size_t)(b * SS + row) * NI + kbase + ck * 8;
      __builtin_amdgcn_global_load_lds((const __attribute__((address_space(1))) void*)src,
          (__attribute__((address_space(3))) void*)(Ah + (size_t)slot * 8), 16, 0, 0);
    }
    #pragma unroll
    for (int i = 0; i < 8; ++i) {
      const int slot = i * 256 + tid;
      const int row = slot >> 4, ck = slot & 15;
      const uint16_t* src = Bs + (size_t)(N0 + row) * NI + kbase + ck * 8;
      __builtin_amdgcn_global_load_lds((const __attribute__((address_space(1))) void*)src,
          (__attribute__((address_space(3))) void*)(Bh + (size_t)slot * 8), 16, 0, 0);
    }
    __syncthreads();
    const int brow = w * 32 + l31;
    const int bbyte = brow * 256;
    const int bmask = brow & 15;
    #pragma unroll
    for (int ks = 0; ks < 8; ++ks) {
      const int sl = ks * 2 + l5;
      bf16x8 bf = *reinterpret_cast<const bf16x8*>((const char*)Bh + bbyte + ((sl ^ bmask) << 4));
      #pragma unroll
      for (int mt = 0; mt < 6; ++mt) {
        const int ar = mt * 32 + l31;
        bf16x8 af = *reinterpret_cast<const bf16x8*>((const char*)Ah + ar * 256 + ((sl ^ (ar & 15)) << 4));
        acc[mt] = __builtin_amdgcn_mfma_f32_32x32x16_bf16(af, bf, acc[mt], 0, 0, 0);
      }
    }
  }
  const int n = N0 + w * 32 + l31;
  const int nck = n >> 3, npos = n & 7;
  #pragma unroll
  for (int mt = 0; mt < 6; ++mt) {
    #pragma unroll
    for (int r = 0; r < 16; ++r) {
      const int m = mt * 32 + (r & 3) + 8 * (r >> 2) + 4 * l5;
      Os[(size_t)(b * SS + m) * NI + ((nck ^ (m & 15)) << 3) + npos] = f2bf(acc[mt][r]);
    }
  }
}

// ---------------- K2 stage-2: s_hd/s_hs/s_ds (192x192, K=256), MFMA ----------------
__global__ __launch_bounds__(384, 1) void k_s2(
    const uint16_t* __restrict__ HH, const uint16_t* __restrict__ HD,
    const uint16_t* __restrict__ dU16, const uint16_t* __restrict__ T216, const uint16_t* __restrict__ TZ16,
    float* __restrict__ s_hd, float* __restrict__ s_hs, float* __restrict__ s_ds) {
  __shared__ __align__(16) uint16_t Ah[192 * 128];   // 48 KB
  __shared__ __align__(16) uint16_t Bh[192 * 128];   // 48 KB
  const int which = blockIdx.x, b = blockIdx.y;
  const uint16_t* As = (which == 2) ? HD : HH;
  const uint16_t* Bs = (which == 0) ? dU16 : (which == 1) ? T216 : TZ16;
  float* Os = (which == 0) ? s_hd : (which == 1) ? s_hs : s_ds;
  const int tid = threadIdx.x, lane = tid & 63, w = tid >> 6;
  const int l31 = lane & 31, l5 = lane >> 5;
  f32x16 acc[6] = {};

  #pragma unroll
  for (int kh = 0; kh < 2; ++kh) {
    const int kbase = kh * 128;
    if (kh) __syncthreads();
    #pragma unroll
    for (int i = 0; i < 8; ++i) {
      const int slot = i * 384 + tid;
      const int row = slot >> 4, ck = slot & 15;
      const uint16_t* src = As + (size_t)(b * SS + row) * NI + kbase + ck * 8;
      __builtin_amdgcn_global_load_lds((const __attribute__((address_space(1))) void*)src,
          (__attribute__((address_space(3))) void*)(Ah + (size_t)slot * 8), 16, 0, 0);
    }
    #pragma unroll
    for (int i = 0; i < 8; ++i) {
      const int slot = i * 384 + tid;
      const int row = slot >> 4, ck = slot & 15;
      const uint16_t* src = Bs + (size_t)(b * SS + row) * NI + kbase + ck * 8;
      __builtin_amdgcn_global_load_lds((const __attribute__((address_space(1))) void*)src,
          (__attribute__((address_space(3))) void*)(Bh + (size_t)slot * 8), 16, 0, 0);
    }
    __syncthreads();
    const int brow = w * 32 + l31;
    const int bbyte = brow * 256;
    const int bmask = brow & 15;
    #pragma unroll
    for (int ks = 0; ks < 8; ++ks) {
      const int sl = ks * 2 + l5;
      bf16x8 bf = *reinterpret_cast<const bf16x8*>((const char*)Bh + bbyte + ((sl ^ bmask) << 4));
      #pragma unroll
      for (int mt = 0; mt < 6; ++mt) {
        const int ar = mt * 32 + l31;
        bf16x8 af = *reinterpret_cast<const bf16x8*>((const char*)Ah + ar * 256 + ((sl ^ (ar & 15)) << 4));
        acc[mt] = __builtin_amdgcn_mfma_f32_32x32x16_bf16(af, bf, acc[mt], 0, 0, 0);
      }
    }
  }
  const int n = w * 32 + l31;
  #pragma unroll
  for (int mt = 0; mt < 6; ++mt) {
    #pragma unroll
    for (int r = 0; r < 16; ++r) {
      const int m = mt * 32 + (r & 3) + 8 * (r >> 2) + 4 * l5;
      Os[(size_t)(b * SS + m) * SS + n] = acc[mt][r];
    }
  }
}

// ---------------- K3: main GEMM — 96h x 96s blocks, 9 waves, 48 KB LDS, 3 blocks/CU ----------------
// grid (192, 4, 4): x=d, y=(hb<<1)|sb, z=b. 576 threads = 9 waves (3 h-strips x 3 s-strips).
__global__ __launch_bounds__(576) void k3_big(
    const uint16_t* __restrict__ HH, const uint16_t* __restrict__ HS,
    const float* __restrict__ h_dep, const float* __restrict__ partial,
    const float* __restrict__ s_hd, const float* __restrict__ s_hs,
    const float* __restrict__ s_ds,
    const float* __restrict__ bias, float* __restrict__ out) {
  __shared__ __align__(16) uint16_t Btile[96 * 128];   // 24 KB (HS rows, swizzled layout)
  __shared__ __align__(16) uint16_t Atile[96 * 128];   // 24 KB (HH*cvec, swizzled layout)
  __shared__ uint16_t cvec[NI];
  const int d = blockIdx.x, hb = blockIdx.y >> 1, sb = blockIdx.y & 1, b = blockIdx.z;
  const int tid = threadIdx.x;
  const int lane = tid & 63, w = tid >> 6;
  const int wh = w / 3, ws = w % 3;
  const int l31 = lane & 31, l5 = lane >> 5;

  if (tid < NI) {
    // partial[] = 2048 chunks of 8192 floats; i-row tid of W_tri = chunks 8*tid..8*tid+7
    float wr = 0.f;
    #pragma unroll
    for (int q = 0; q < 8; ++q) wr += partial[8 * tid + q];
    cvec[tid] = f2bf(wr * h_dep[(b * SS + d) * NI + tid]);
  }
  __syncthreads();

  f32x16 acc = {};

  #pragma unroll
  for (int half = 0; half < 2; ++half) {
    const int kbase = half * 128;
    if (half) __syncthreads();
    // B-tile: 96 HS rows (swizzled storage) -> linear LDS copy. 1536 slots / 576 thr.
    #pragma unroll
    for (int i = 0; i < 3; ++i) {
      const int slot = i * 576 + tid;
      if (slot < 1536) {
        const int row = slot >> 4;
        const uint16_t* src = HS + ((size_t)(b * SS + sb * 96 + row) << 8) + kbase + (slot & 15) * 8;
        __builtin_amdgcn_global_load_lds(
            (const __attribute__((address_space(1))) void*)src,
            (__attribute__((address_space(3))) void*)(Btile + (size_t)slot * 8),
            16, 0, 0);
      }
    }
    // A-tile: HH (swizzled storage) * cvec -> LDS (linear write = swizzled layout)
    #pragma unroll
    for (int i = 0; i < 3; ++i) {
      const int slot = i * 576 + tid;
      if (slot < 1536) {
        const int row = slot >> 4;
        const int kc = slot & 15;
        const int lcl = kc ^ (row & 15);
        const uint4 cv4 = *(const uint4*)(cvec + kbase + lcl * 8);
        const uint4 hh4 = *(const uint4*)(HH + ((size_t)(b * SS + hb * 96 + row) << 8) + kbase + kc * 8);
        uint4 a4;
        a4.x = bfmul2(hh4.x, cv4.x);
        a4.y = bfmul2(hh4.y, cv4.y);
        a4.z = bfmul2(hh4.z, cv4.z);
        a4.w = bfmul2(hh4.w, cv4.w);
        *(uint4*)((char*)Atile + (size_t)slot * 16) = a4;
      }
    }
    __syncthreads();
    const int arow = wh * 32 + l31;
    const int abyte = arow * 256;
    const int amask = arow & 15;
    const int brow = ws * 32 + l31;
    const int bbyte = brow * 256;
    const int bmask = brow & 15;
    #pragma unroll
    for (int ks = 0; ks < 8; ++ks) {
      const int sl = ks * 2 + l5;
      bf16x8 af = *reinterpret_cast<const bf16x8*>((const char*)Atile + abyte + ((sl ^ amask) << 4));
      bf16x8 bf = *reinterpret_cast<const bf16x8*>((const char*)Btile + bbyte + ((sl ^ bmask) << 4));
      acc = __builtin_amdgcn_mfma_f32_32x32x16_bf16(af, bf, acc, 0, 0, 0);
    }
  }

  // epilogue: + s_hd[b,h,d] + bias + s_hs[b,h,s] + s_ds[b,d,s]
  const float bias0 = bias[0];
  const int s = sb * 96 + ws * 32 + l31;
  const float dsv = s_ds[(b * SS + d) * SS + s];
  #pragma unroll
  for (int r = 0; r < 16; ++r) {
    const int h = hb * 96 + wh * 32 + (r & 3) + 8 * (r >> 2) + 4 * l5;
    const float chd = s_hd[(b * SS + h) * SS + d] + bias0;
    const float v = acc[r] + chd + s_hs[(b * SS + h) * SS + s] + dsv;
    out[((size_t)(b * SS + h) * SS + d) * SS + s] = v;
  }
}

extern "C" void kernel_launch(void* const* d_in, const int* in_sizes, int n_in,
                              void* d_out, int out_size, void* d_ws, size_t ws_size,
                              hipStream_t stream) {
  const float* h_head = (const float*)d_in[0];
  const float* h_dep  = (const float*)d_in[1];
  const float* h_sib  = (const float*)d_in[2];
  const float* W_tri  = (const float*)d_in[3];
  const float* U_hd   = (const float*)d_in[4];
  const float* V_hs   = (const float*)d_in[5];
  const float* Z_ds   = (const float*)d_in[6];
  const float* bias   = (const float*)d_in[7];
  float* out = (float*)d_out;

  float* ws = (float*)d_ws;
  float* partial = ws;          ws += 2048;
  float* s_hd    = ws;          ws += NB * SS * SS;
  float* s_hs    = ws;          ws += NB * SS * SS;
  float* s_ds    = ws;          ws += NB * SS * SS;
  uint16_t* HH   = (uint16_t*)ws;
  uint16_t* HD   = HH + NB * SS * NI;
  uint16_t* HS   = HD + NB * SS * NI;
  uint16_t* U16  = HS + NB * SS * NI;
  uint16_t* V16  = U16 + NI * NI;
  uint16_t* Z16  = V16 + NI * NI;
  uint16_t* dU16 = Z16 + NI * NI;
  uint16_t* T216 = dU16 + NB * SS * NI;
  uint16_t* TZ16 = T216 + NB * SS * NI;

  k0<<<2176, 256, 0, stream>>>(W_tri, h_head, h_dep, h_sib, U_hd, V_hs, Z_ds,
                               partial, HH, HD, HS, U16, V16, Z16);
  k_s1<<<dim3(3, 2, NB), 256, 0, stream>>>(HD, HS, U16, V16, Z16, dU16, T216, TZ16);
  k_s2<<<dim3(3, NB), 384, 0, stream>>>(HH, HD, dU16, T216, TZ16, s_hd, s_hs, s_ds);
  k3_big<<<dim3(SS, 4, NB), 576, 0, stream>>>(HH, HS, h_dep, partial,
                                              s_hd, s_hs, s_ds, bias, out);
}